// Round 1
// baseline (956.180 us; speedup 1.0000x reference)
//
#include <hip/hip_runtime.h>

// Problem constants
// B=1024, T=128, F=1024, Z=256, TXT=768, H=8, d=128
#define EPS 1e-5f

// ======================================================================
// Generic tiled f32 GEMM (NT): C = scale * (A @ W^T) + bias
//   A: [M,K] row-major, lda   (+ z*Aoffz elements)
//   W: [N,K] row-major, ldw   (+ z*Woffz)
//   C: [M,N] row-major, ldc   (+ z*Coffz)
// Tile 64x64, BK=16, 256 threads, 4x4 per thread. All dims divisible.
// ======================================================================
#define TILE 64
#define BKK 16

__global__ __launch_bounds__(256)
void gemm_nt(const float* __restrict__ A, int lda, int Aoffz,
             const float* __restrict__ W, int ldw, int Woffz,
             float* __restrict__ C, int ldc, int Coffz,
             const float* __restrict__ bias, int boffz,
             float scale, int M, int N, int K)
{
    int z = blockIdx.z;
    A += (size_t)z * Aoffz;
    W += (size_t)z * Woffz;
    C += (size_t)z * Coffz;
    int bm = blockIdx.y * TILE;
    int bn = blockIdx.x * TILE;

    __shared__ float As[BKK][TILE + 4];
    __shared__ float Ws[BKK][TILE + 4];

    int tid = threadIdx.x;
    int tx = tid & 15, ty = tid >> 4;
    int r0 = ty * 4, c0 = tx * 4;
    int lm = tid >> 2;           // 0..63 tile row
    int lk = (tid & 3) * 4;      // 0,4,8,12

    float acc[4][4] = {};

    for (int kt = 0; kt < K; kt += BKK) {
        float4 a4 = *(const float4*)&A[(size_t)(bm + lm) * lda + kt + lk];
        float4 w4 = *(const float4*)&W[(size_t)(bn + lm) * ldw + kt + lk];
        As[lk + 0][lm] = a4.x; As[lk + 1][lm] = a4.y;
        As[lk + 2][lm] = a4.z; As[lk + 3][lm] = a4.w;
        Ws[lk + 0][lm] = w4.x; Ws[lk + 1][lm] = w4.y;
        Ws[lk + 2][lm] = w4.z; Ws[lk + 3][lm] = w4.w;
        __syncthreads();
        #pragma unroll
        for (int kk = 0; kk < BKK; ++kk) {
            float4 av = *(const float4*)&As[kk][r0];
            float4 wv = *(const float4*)&Ws[kk][c0];
            float a_[4] = {av.x, av.y, av.z, av.w};
            float w_[4] = {wv.x, wv.y, wv.z, wv.w};
            #pragma unroll
            for (int i = 0; i < 4; ++i)
                #pragma unroll
                for (int j = 0; j < 4; ++j)
                    acc[i][j] += a_[i] * w_[j];
        }
        __syncthreads();
    }

    float bsv[4] = {0.f, 0.f, 0.f, 0.f};
    if (bias) {
        const float* bz = bias + (size_t)z * boffz;
        float4 b4 = *(const float4*)&bz[bn + c0];
        bsv[0] = b4.x; bsv[1] = b4.y; bsv[2] = b4.z; bsv[3] = b4.w;
    }
    #pragma unroll
    for (int i = 0; i < 4; ++i) {
        float4 o;
        o.x = acc[i][0] * scale + bsv[0];
        o.y = acc[i][1] * scale + bsv[1];
        o.z = acc[i][2] * scale + bsv[2];
        o.w = acc[i][3] * scale + bsv[3];
        *(float4*)&C[(size_t)(bm + r0 + i) * ldc + bn + c0] = o;
    }
}

// ======================================================================
// Generic tiled f32 GEMM (NN): C = scale * (A @ B) + bias
//   B: [K,N] row-major, ldb (+ z*Boffz)
// ======================================================================
__global__ __launch_bounds__(256)
void gemm_nn(const float* __restrict__ A, int lda, int Aoffz,
             const float* __restrict__ Bm, int ldb, int Boffz,
             float* __restrict__ C, int ldc, int Coffz,
             const float* __restrict__ bias, int boffz,
             float scale, int M, int N, int K)
{
    int z = blockIdx.z;
    A += (size_t)z * Aoffz;
    Bm += (size_t)z * Boffz;
    C += (size_t)z * Coffz;
    int bm = blockIdx.y * TILE;
    int bn = blockIdx.x * TILE;

    __shared__ float As[BKK][TILE + 4];
    __shared__ float Bs[BKK][TILE + 4];

    int tid = threadIdx.x;
    int tx = tid & 15, ty = tid >> 4;
    int r0 = ty * 4, c0 = tx * 4;
    int lm = tid >> 2;
    int lk = (tid & 3) * 4;
    int brow = tid >> 4;          // 0..15 (k within tile)
    int bcol = (tid & 15) * 4;    // 0..60

    float acc[4][4] = {};

    for (int kt = 0; kt < K; kt += BKK) {
        float4 a4 = *(const float4*)&A[(size_t)(bm + lm) * lda + kt + lk];
        float4 b4 = *(const float4*)&Bm[(size_t)(kt + brow) * ldb + bn + bcol];
        As[lk + 0][lm] = a4.x; As[lk + 1][lm] = a4.y;
        As[lk + 2][lm] = a4.z; As[lk + 3][lm] = a4.w;
        *(float4*)&Bs[brow][bcol] = b4;
        __syncthreads();
        #pragma unroll
        for (int kk = 0; kk < BKK; ++kk) {
            float4 av = *(const float4*)&As[kk][r0];
            float4 wv = *(const float4*)&Bs[kk][c0];
            float a_[4] = {av.x, av.y, av.z, av.w};
            float w_[4] = {wv.x, wv.y, wv.z, wv.w};
            #pragma unroll
            for (int i = 0; i < 4; ++i)
                #pragma unroll
                for (int j = 0; j < 4; ++j)
                    acc[i][j] += a_[i] * w_[j];
        }
        __syncthreads();
    }

    float bsv[4] = {0.f, 0.f, 0.f, 0.f};
    if (bias) {
        const float* bz = bias + (size_t)z * boffz;
        float4 b4 = *(const float4*)&bz[bn + c0];
        bsv[0] = b4.x; bsv[1] = b4.y; bsv[2] = b4.z; bsv[3] = b4.w;
    }
    #pragma unroll
    for (int i = 0; i < 4; ++i) {
        float4 o;
        o.x = acc[i][0] * scale + bsv[0];
        o.y = acc[i][1] * scale + bsv[1];
        o.z = acc[i][2] * scale + bsv[2];
        o.w = acc[i][3] * scale + bsv[3];
        *(float4*)&C[(size_t)(bm + r0 + i) * ldc + bn + c0] = o;
    }
}

// ======================================================================
// Block reduction helper: sum two values over 256 threads (4 waves)
// ======================================================================
__device__ inline void block_reduce2(float& a, float& b, float* sred)
{
    #pragma unroll
    for (int off = 32; off; off >>= 1) {
        a += __shfl_xor(a, off);
        b += __shfl_xor(b, off);
    }
    int w = threadIdx.x >> 6, lane = threadIdx.x & 63;
    if (lane == 0) { sred[w * 2] = a; sred[w * 2 + 1] = b; }
    __syncthreads();
    a = sred[0] + sred[2] + sred[4] + sred[6];
    b = sred[1] + sred[3] + sred[5] + sred[7];
}

// ======================================================================
// rowops1: out = LN(h1)*g+b, then FiLM: *(1+gamma)+beta.  One block per row.
// ======================================================================
__global__ __launch_bounds__(256)
void rowops1(const float* __restrict__ h1, const float* __restrict__ gam,
             const float* __restrict__ bet, const float* __restrict__ g,
             const float* __restrict__ bta, float* __restrict__ out)
{
    __shared__ float sred[8];
    int b = blockIdx.x, tid = threadIdx.x;
    const float4 v = ((const float4*)(h1 + (size_t)b * 1024))[tid];
    float s  = v.x + v.y + v.z + v.w;
    float ss = v.x * v.x + v.y * v.y + v.z * v.z + v.w * v.w;
    block_reduce2(s, ss, sred);
    float mu  = s * (1.f / 1024.f);
    float var = ss * (1.f / 1024.f) - mu * mu;
    float rs  = rsqrtf(var + EPS);
    float4 gv = ((const float4*)g)[tid];
    float4 bv = ((const float4*)bta)[tid];
    float4 ga = ((const float4*)(gam + (size_t)b * 1024))[tid];
    float4 be = ((const float4*)(bet + (size_t)b * 1024))[tid];
    float4 o;
    o.x = ((v.x - mu) * rs * gv.x + bv.x) * (1.f + ga.x) + be.x;
    o.y = ((v.y - mu) * rs * gv.y + bv.y) * (1.f + ga.y) + be.y;
    o.z = ((v.z - mu) * rs * gv.z + bv.z) * (1.f + ga.z) + be.z;
    o.w = ((v.w - mu) * rs * gv.w + bv.w) * (1.f + ga.w) + be.w;
    ((float4*)(out + (size_t)b * 1024))[tid] = o;
}

// ======================================================================
// rowops2: final = gelu(out + LN(attn_out)*g+b)  (exact gelu, erf)
// ======================================================================
__global__ __launch_bounds__(256)
void rowops2(const float* __restrict__ outp, const float* __restrict__ ao,
             const float* __restrict__ g, const float* __restrict__ bta,
             float* __restrict__ dst)
{
    __shared__ float sred[8];
    int b = blockIdx.x, tid = threadIdx.x;
    const float4 v = ((const float4*)(ao + (size_t)b * 1024))[tid];
    float s  = v.x + v.y + v.z + v.w;
    float ss = v.x * v.x + v.y * v.y + v.z * v.z + v.w * v.w;
    block_reduce2(s, ss, sred);
    float mu  = s * (1.f / 1024.f);
    float var = ss * (1.f / 1024.f) - mu * mu;
    float rs  = rsqrtf(var + EPS);
    float4 gv = ((const float4*)g)[tid];
    float4 bv = ((const float4*)bta)[tid];
    float4 ov = ((const float4*)(outp + (size_t)b * 1024))[tid];
    float y0 = ov.x + ((v.x - mu) * rs * gv.x + bv.x);
    float y1 = ov.y + ((v.y - mu) * rs * gv.y + bv.y);
    float y2 = ov.z + ((v.z - mu) * rs * gv.z + bv.z);
    float y3 = ov.w + ((v.w - mu) * rs * gv.w + bv.w);
    float4 o;
    o.x = 0.5f * y0 * (1.f + erff(y0 * 0.70710678118654752f));
    o.y = 0.5f * y1 * (1.f + erff(y1 * 0.70710678118654752f));
    o.z = 0.5f * y2 * (1.f + erff(y2 * 0.70710678118654752f));
    o.w = 0.5f * y3 * (1.f + erff(y3 * 0.70710678118654752f));
    ((float4*)(dst + (size_t)b * 1024))[tid] = o;
}

// ======================================================================
// attn_kernel: per-row-b scores + softmax + attn-weighted text features.
//   qt:    [B, 8, 768]  (q projected into text space, pre-scaled by 1/sqrt(d))
//   tf:    [B, 128, 768]
//   ctxtf: [B, 8, 768]  output: sum_t attn[b,h,t] * tf[b,t,:]
// One block (256 thr = 4 waves) per b. Pass1: each wave does 32 t-rows, all
// heads (lane covers c = 4*lane + 256k). Pass2: each wave owns 2 heads, all
// rows (re-read mostly L1/L2-resident since 4 waves stream in lockstep).
// ======================================================================
__global__ __launch_bounds__(256)
void attn_kernel(const float* __restrict__ tf, const float* __restrict__ qt,
                 const int* __restrict__ att, float* __restrict__ ctxtf)
{
    int b = blockIdx.x;
    int tid = threadIdx.x, lane = tid & 63, w = tid >> 6;
    __shared__ float s_sc[8][128];

    const float* tfb = tf + (size_t)b * 98304;
    const float* qtb = qt + (size_t)b * 6144;

    // q-tilde in registers: qv[h][k] covers c = 4*lane + 256*k
    float4 qv[8][3];
    #pragma unroll
    for (int h = 0; h < 8; ++h)
        #pragma unroll
        for (int k = 0; k < 3; ++k)
            qv[h][k] = *(const float4*)&qtb[h * 768 + 4 * lane + 256 * k];

    // ---- pass 1: scores ----
    for (int t = w; t < 128; t += 4) {
        float4 x[3];
        #pragma unroll
        for (int k = 0; k < 3; ++k)
            x[k] = *(const float4*)&tfb[t * 768 + 4 * lane + 256 * k];
        float s[8];
        #pragma unroll
        for (int h = 0; h < 8; ++h) {
            s[h] = 0.f;
            #pragma unroll
            for (int k = 0; k < 3; ++k)
                s[h] += qv[h][k].x * x[k].x + qv[h][k].y * x[k].y +
                        qv[h][k].z * x[k].z + qv[h][k].w * x[k].w;
        }
        #pragma unroll
        for (int h = 0; h < 8; ++h)
            #pragma unroll
            for (int off = 32; off; off >>= 1)
                s[h] += __shfl_xor(s[h], off);
        if (lane == 0) {
            #pragma unroll
            for (int h = 0; h < 8; ++h) s_sc[h][t] = s[h];
        }
    }
    __syncthreads();

    // ---- mask + softmax over T: wave w handles heads 2w, 2w+1 ----
    int m0 = att[b * 128 + lane];
    int m1 = att[b * 128 + 64 + lane];
    #pragma unroll
    for (int hh = 0; hh < 2; ++hh) {
        int h = 2 * w + hh;
        float x0 = m0 ? s_sc[h][lane]      : -INFINITY;
        float x1 = m1 ? s_sc[h][lane + 64] : -INFINITY;
        float mx = fmaxf(x0, x1);
        #pragma unroll
        for (int off = 32; off; off >>= 1)
            mx = fmaxf(mx, __shfl_xor(mx, off));
        float e0 = m0 ? __expf(x0 - mx) : 0.f;
        float e1 = m1 ? __expf(x1 - mx) : 0.f;
        float sm = e0 + e1;
        #pragma unroll
        for (int off = 32; off; off >>= 1)
            sm += __shfl_xor(sm, off);
        float inv = 1.f / sm;
        s_sc[h][lane]      = e0 * inv;
        s_sc[h][lane + 64] = e1 * inv;
    }
    __syncthreads();

    // ---- pass 2: ctxtf accumulation, wave owns heads 2w, 2w+1 ----
    int h0 = 2 * w;
    float4 acc[2][3] = {};
    for (int t = 0; t < 128; ++t) {
        float4 x[3];
        #pragma unroll
        for (int k = 0; k < 3; ++k)
            x[k] = *(const float4*)&tfb[t * 768 + 4 * lane + 256 * k];
        float a0 = s_sc[h0][t];
        float a1 = s_sc[h0 + 1][t];
        #pragma unroll
        for (int k = 0; k < 3; ++k) {
            acc[0][k].x += a0 * x[k].x; acc[0][k].y += a0 * x[k].y;
            acc[0][k].z += a0 * x[k].z; acc[0][k].w += a0 * x[k].w;
            acc[1][k].x += a1 * x[k].x; acc[1][k].y += a1 * x[k].y;
            acc[1][k].z += a1 * x[k].z; acc[1][k].w += a1 * x[k].w;
        }
    }
    #pragma unroll
    for (int j = 0; j < 2; ++j)
        #pragma unroll
        for (int k = 0; k < 3; ++k)
            *(float4*)&ctxtf[(size_t)b * 6144 + (h0 + j) * 768 + 4 * lane + 256 * k] = acc[j][k];
}

// ======================================================================
// launch
// ======================================================================
extern "C" void kernel_launch(void* const* d_in, const int* in_sizes, int n_in,
                              void* d_out, int out_size, void* d_ws, size_t ws_size,
                              hipStream_t stream)
{
    const float* x    = (const float*)d_in[0];
    const float* zc   = (const float*)d_in[1];
    const float* tf   = (const float*)d_in[2];
    const int*   att  = (const int*)d_in[3];
    const float* Wg   = (const float*)d_in[4];
    const float* bg   = (const float*)d_in[5];
    const float* Wb   = (const float*)d_in[6];
    const float* bb   = (const float*)d_in[7];
    const float* Wl   = (const float*)d_in[8];
    const float* bl   = (const float*)d_in[9];
    const float* ln1g = (const float*)d_in[10];
    const float* ln1b = (const float*)d_in[11];
    const float* Wq   = (const float*)d_in[12];
    const float* bq   = (const float*)d_in[13];
    const float* Wk   = (const float*)d_in[14];
    // d_in[15] = bk: unused — adds a t-independent constant to scores,
    // softmax is shift-invariant, so it cancels exactly.
    const float* Wv   = (const float*)d_in[16];
    const float* bv   = (const float*)d_in[17];
    const float* Wo   = (const float*)d_in[18];
    const float* bo   = (const float*)d_in[19];
    const float* ln2g = (const float*)d_in[20];
    const float* ln2b = (const float*)d_in[21];

    float* ws = (float*)d_ws;
    const size_t M1 = 1u << 20;  // 1024*1024 elements
    float* OUT   = ws;            // [B,F] modulated linear output (live to end)
    float* H1    = ws + 1 * M1;   // [B,F] linear pre-LN; reused for CTX later
    float* GAM   = ws + 2 * M1;   // [B,F] FiLM gamma; reused for attn_out later
    float* BET   = ws + 3 * M1;   // [B,F] FiLM beta
    float* Q     = ws + 4 * M1;   // [B,F] query
    float* QT    = ws + 5 * M1;   // [B,8,768] q in text space (6M elements)
    float* CTXTF = ws + 11 * M1;  // [B,8,768] attn-weighted text feats (6M)
    float* CTX   = H1;            // [B,F]
    float* AO    = GAM;           // [B,F]

    dim3 blk(256);

    // h1 = x @ Wl^T + bl
    gemm_nt<<<dim3(16, 16, 1), blk, 0, stream>>>(x, 1024, 0, Wl, 1024, 0,
        H1, 1024, 0, bl, 0, 1.f, 1024, 1024, 1024);
    // gamma = z @ Wg^T + bg ; beta = z @ Wb^T + bb
    gemm_nt<<<dim3(16, 16, 1), blk, 0, stream>>>(zc, 256, 0, Wg, 256, 0,
        GAM, 1024, 0, bg, 0, 1.f, 1024, 1024, 256);
    gemm_nt<<<dim3(16, 16, 1), blk, 0, stream>>>(zc, 256, 0, Wb, 256, 0,
        BET, 1024, 0, bb, 0, 1.f, 1024, 1024, 256);
    // out = LN(h1)*(1+gamma)+beta
    rowops1<<<dim3(1024), blk, 0, stream>>>(H1, GAM, BET, ln1g, ln1b, OUT);
    // q = out @ Wq^T + bq
    gemm_nt<<<dim3(16, 16, 1), blk, 0, stream>>>(OUT, 1024, 0, Wq, 1024, 0,
        Q, 1024, 0, bq, 0, 1.f, 1024, 1024, 1024);
    // qt[b,h,:] = (1/sqrt(128)) * q[b,h,:] @ Wk_h    (batched over h)
    gemm_nn<<<dim3(12, 16, 8), blk, 0, stream>>>(Q, 1024, 128, Wk, 768, 98304,
        QT, 6144, 768, nullptr, 0, 0.08838834764831845f, 1024, 768, 128);
    // scores/softmax/weighted-sum of raw text features
    attn_kernel<<<dim3(1024), blk, 0, stream>>>(tf, QT, att, CTXTF);
    // ctx[b,h*128+d] = ctxtf[b,h,:] @ Wv_h^T + bv   (batched over h)
    gemm_nt<<<dim3(2, 16, 8), blk, 0, stream>>>(CTXTF, 6144, 768, Wv, 768, 98304,
        CTX, 1024, 128, bv, 128, 1.f, 1024, 128, 768);
    // attn_out = ctx @ Wo^T + bo
    gemm_nt<<<dim3(16, 16, 1), blk, 0, stream>>>(CTX, 1024, 0, Wo, 1024, 0,
        AO, 1024, 0, bo, 0, 1.f, 1024, 1024, 1024);
    // final = gelu(out + LN(attn_out))
    rowops2<<<dim3(1024), blk, 0, stream>>>(OUT, AO, ln2g, ln2b, (float*)d_out);
}

// Round 2
// 787.768 us; speedup vs baseline: 1.2138x; 1.2138x over previous
//
#include <hip/hip_runtime.h>

// B=1024, T=128, F=1024, Z=256, TXT=768, H=8, d=128
#define EPS 1e-5f

typedef __bf16 bf16x8 __attribute__((ext_vector_type(8)));
typedef float f32x4 __attribute__((ext_vector_type(4)));
typedef ushort ushort8 __attribute__((ext_vector_type(8)));

static __device__ __forceinline__ ushort f2bf(float x) {
    union { float f; unsigned u; } v; v.f = x;
    unsigned r = v.u + 0x7fffu + ((v.u >> 16) & 1u);  // RNE
    return (ushort)(r >> 16);
}

// ======================================================================
// MFMA GEMM (NT): C = scale * (A_f32 @ W_bf16^T) + bias
//   A: [M,K] f32 row-major (converted to bf16 during staging)
//   W: [N,K] bf16 row-major
// Tile 64x64, BK=64, 256 thr = 4 waves (2x2 wave grid, 32x32 per wave,
// 2x2 fragments of 16x16x32). LDS rows padded to 72 (144B -> 2-way bank
// aliasing only, free). Grid: (N/64, M/64, Z).
// ======================================================================
__global__ __launch_bounds__(256)
void gemm_nt_mfma(const float* __restrict__ A, int lda, int Aoffz,
                  const ushort* __restrict__ W, int ldw, int Woffz,
                  float* __restrict__ C, int ldc, int Coffz,
                  const float* __restrict__ bias, int boffz,
                  float scale, int K)
{
    const int z = blockIdx.z;
    A += (size_t)z * Aoffz;
    W += (size_t)z * Woffz;
    C += (size_t)z * Coffz;
    const int bm = blockIdx.y * 64, bn = blockIdx.x * 64;

    __shared__ ushort As[64][72];
    __shared__ ushort Bs[64][72];

    const int tid  = threadIdx.x;
    const int lane = tid & 63, wv = tid >> 6;
    const int wm = (wv >> 1) * 32, wn = (wv & 1) * 32;

    // staging coords: thread covers row srow, 16 elements from scol
    const int srow = tid >> 2;
    const int scol = (tid & 3) * 16;
    const float*  Agp = A + (size_t)(bm + srow) * lda + scol;
    const ushort* Wgp = W + (size_t)(bn + srow) * ldw + scol;

    // fragment coords (A row / B col = lane&15, k = (lane>>4)*8 + j)
    const int fr = lane & 15, fk = (lane >> 4) * 8;

    f32x4 acc[2][2] = {};

    for (int kt = 0; kt < K; kt += 64) {
        f32x4 a0 = *(const f32x4*)(Agp + kt + 0);
        f32x4 a1 = *(const f32x4*)(Agp + kt + 4);
        f32x4 a2 = *(const f32x4*)(Agp + kt + 8);
        f32x4 a3 = *(const f32x4*)(Agp + kt + 12);
        ushort8 b0 = *(const ushort8*)(Wgp + kt);
        ushort8 b1 = *(const ushort8*)(Wgp + kt + 8);

        ushort8 u0, u1;
        u0[0]=f2bf(a0[0]); u0[1]=f2bf(a0[1]); u0[2]=f2bf(a0[2]); u0[3]=f2bf(a0[3]);
        u0[4]=f2bf(a1[0]); u0[5]=f2bf(a1[1]); u0[6]=f2bf(a1[2]); u0[7]=f2bf(a1[3]);
        u1[0]=f2bf(a2[0]); u1[1]=f2bf(a2[1]); u1[2]=f2bf(a2[2]); u1[3]=f2bf(a2[3]);
        u1[4]=f2bf(a3[0]); u1[5]=f2bf(a3[1]); u1[6]=f2bf(a3[2]); u1[7]=f2bf(a3[3]);

        *(ushort8*)&As[srow][scol]     = u0;
        *(ushort8*)&As[srow][scol + 8] = u1;
        *(ushort8*)&Bs[srow][scol]     = b0;
        *(ushort8*)&Bs[srow][scol + 8] = b1;
        __syncthreads();

        #pragma unroll
        for (int ks = 0; ks < 64; ks += 32) {
            bf16x8 af0 = *(const bf16x8*)&As[wm + fr][ks + fk];
            bf16x8 af1 = *(const bf16x8*)&As[wm + 16 + fr][ks + fk];
            bf16x8 bf0 = *(const bf16x8*)&Bs[wn + fr][ks + fk];
            bf16x8 bf1 = *(const bf16x8*)&Bs[wn + 16 + fr][ks + fk];
            acc[0][0] = __builtin_amdgcn_mfma_f32_16x16x32_bf16(af0, bf0, acc[0][0], 0, 0, 0);
            acc[0][1] = __builtin_amdgcn_mfma_f32_16x16x32_bf16(af0, bf1, acc[0][1], 0, 0, 0);
            acc[1][0] = __builtin_amdgcn_mfma_f32_16x16x32_bf16(af1, bf0, acc[1][0], 0, 0, 0);
            acc[1][1] = __builtin_amdgcn_mfma_f32_16x16x32_bf16(af1, bf1, acc[1][1], 0, 0, 0);
        }
        __syncthreads();
    }

    // epilogue: D col = lane&15, row = (lane>>4)*4 + reg
    const int rbase = (lane >> 4) * 4;
    #pragma unroll
    for (int mi = 0; mi < 2; ++mi) {
        #pragma unroll
        for (int ni = 0; ni < 2; ++ni) {
            const int col = bn + wn + ni * 16 + fr;
            const float bvv = bias ? (bias + (size_t)z * boffz)[col] : 0.f;
            #pragma unroll
            for (int r = 0; r < 4; ++r) {
                const int row = bm + wm + mi * 16 + rbase + r;
                C[(size_t)row * ldc + col] = acc[mi][ni][r] * scale + bvv;
            }
        }
    }
}

// ======================================================================
// prep: f32 -> bf16 elementwise (n % 4 == 0)
// ======================================================================
__global__ __launch_bounds__(256)
void cvt_bf16(const float* __restrict__ src, ushort* __restrict__ dst, int n)
{
    int i = (blockIdx.x * 256 + threadIdx.x) * 4;
    if (i < n) {
        f32x4 v = *(const f32x4*)(src + i);
        ushort4 o;
        o.x = f2bf(v[0]); o.y = f2bf(v[1]); o.z = f2bf(v[2]); o.w = f2bf(v[3]);
        *(ushort4*)(dst + i) = o;
    }
}

// ======================================================================
// prep: Wk [1024,768] f32 (row h*128+d, col c) -> WkT [8][768][128] bf16
// Grid (24, 4, 8), block 256 (=32x8), LDS 32x33 transpose tile.
// ======================================================================
__global__ __launch_bounds__(256)
void transpose_wk(const float* __restrict__ Wk, ushort* __restrict__ WkT)
{
    __shared__ ushort s[32][33];
    const int h  = blockIdx.z;
    const int c0 = blockIdx.x * 32, d0 = blockIdx.y * 32;
    const int tx = threadIdx.x & 31, ty = threadIdx.x >> 5;
    #pragma unroll
    for (int i = 0; i < 4; ++i) {
        int d = d0 + ty + i * 8;
        s[ty + i * 8][tx] = f2bf(Wk[(size_t)(h * 128 + d) * 768 + c0 + tx]);
    }
    __syncthreads();
    #pragma unroll
    for (int i = 0; i < 4; ++i) {
        int c = c0 + ty + i * 8;
        WkT[((size_t)h * 768 + c) * 128 + d0 + tx] = s[tx][ty + i * 8];
    }
}

// ======================================================================
// Block reduction helper: sum two values over 256 threads (4 waves)
// ======================================================================
__device__ inline void block_reduce2(float& a, float& b, float* sred)
{
    #pragma unroll
    for (int off = 32; off; off >>= 1) {
        a += __shfl_xor(a, off);
        b += __shfl_xor(b, off);
    }
    int w = threadIdx.x >> 6, lane = threadIdx.x & 63;
    if (lane == 0) { sred[w * 2] = a; sred[w * 2 + 1] = b; }
    __syncthreads();
    a = sred[0] + sred[2] + sred[4] + sred[6];
    b = sred[1] + sred[3] + sred[5] + sred[7];
}

// ======================================================================
// rowops1: out = LN(h1)*g+b, then FiLM: *(1+gamma)+beta.  One block per row.
// ======================================================================
__global__ __launch_bounds__(256)
void rowops1(const float* __restrict__ h1, const float* __restrict__ gam,
             const float* __restrict__ bet, const float* __restrict__ g,
             const float* __restrict__ bta, float* __restrict__ out)
{
    __shared__ float sred[8];
    int b = blockIdx.x, tid = threadIdx.x;
    const float4 v = ((const float4*)(h1 + (size_t)b * 1024))[tid];
    float s  = v.x + v.y + v.z + v.w;
    float ss = v.x * v.x + v.y * v.y + v.z * v.z + v.w * v.w;
    block_reduce2(s, ss, sred);
    float mu  = s * (1.f / 1024.f);
    float var = ss * (1.f / 1024.f) - mu * mu;
    float rs  = rsqrtf(var + EPS);
    float4 gv = ((const float4*)g)[tid];
    float4 bv = ((const float4*)bta)[tid];
    float4 ga = ((const float4*)(gam + (size_t)b * 1024))[tid];
    float4 be = ((const float4*)(bet + (size_t)b * 1024))[tid];
    float4 o;
    o.x = ((v.x - mu) * rs * gv.x + bv.x) * (1.f + ga.x) + be.x;
    o.y = ((v.y - mu) * rs * gv.y + bv.y) * (1.f + ga.y) + be.y;
    o.z = ((v.z - mu) * rs * gv.z + bv.z) * (1.f + ga.z) + be.z;
    o.w = ((v.w - mu) * rs * gv.w + bv.w) * (1.f + ga.w) + be.w;
    ((float4*)(out + (size_t)b * 1024))[tid] = o;
}

// ======================================================================
// rowops2: final = gelu(out + LN(attn_out)*g+b)  (exact gelu, erf)
// ======================================================================
__global__ __launch_bounds__(256)
void rowops2(const float* __restrict__ outp, const float* __restrict__ ao,
             const float* __restrict__ g, const float* __restrict__ bta,
             float* __restrict__ dst)
{
    __shared__ float sred[8];
    int b = blockIdx.x, tid = threadIdx.x;
    const float4 v = ((const float4*)(ao + (size_t)b * 1024))[tid];
    float s  = v.x + v.y + v.z + v.w;
    float ss = v.x * v.x + v.y * v.y + v.z * v.z + v.w * v.w;
    block_reduce2(s, ss, sred);
    float mu  = s * (1.f / 1024.f);
    float var = ss * (1.f / 1024.f) - mu * mu;
    float rs  = rsqrtf(var + EPS);
    float4 gv = ((const float4*)g)[tid];
    float4 bv = ((const float4*)bta)[tid];
    float4 ov = ((const float4*)(outp + (size_t)b * 1024))[tid];
    float y0 = ov.x + ((v.x - mu) * rs * gv.x + bv.x);
    float y1 = ov.y + ((v.y - mu) * rs * gv.y + bv.y);
    float y2 = ov.z + ((v.z - mu) * rs * gv.z + bv.z);
    float y3 = ov.w + ((v.w - mu) * rs * gv.w + bv.w);
    float4 o;
    o.x = 0.5f * y0 * (1.f + erff(y0 * 0.70710678118654752f));
    o.y = 0.5f * y1 * (1.f + erff(y1 * 0.70710678118654752f));
    o.z = 0.5f * y2 * (1.f + erff(y2 * 0.70710678118654752f));
    o.w = 0.5f * y3 * (1.f + erff(y3 * 0.70710678118654752f));
    ((float4*)(dst + (size_t)b * 1024))[tid] = o;
}

// ======================================================================
// attn_kernel: per-row-b scores + softmax + attn-weighted text features.
//   qt:    [B, 8, 768]  (q projected into text space, pre-scaled by 1/sqrt(d))
//   tf:    [B, 128, 768]
//   ctxtf: [B, 8, 768]  output: sum_t attn[b,h,t] * tf[b,t,:]
// ======================================================================
__global__ __launch_bounds__(256)
void attn_kernel(const float* __restrict__ tf, const float* __restrict__ qt,
                 const int* __restrict__ att, float* __restrict__ ctxtf)
{
    int b = blockIdx.x;
    int tid = threadIdx.x, lane = tid & 63, w = tid >> 6;
    __shared__ float s_sc[8][128];

    const float* tfb = tf + (size_t)b * 98304;
    const float* qtb = qt + (size_t)b * 6144;

    float4 qv[8][3];
    #pragma unroll
    for (int h = 0; h < 8; ++h)
        #pragma unroll
        for (int k = 0; k < 3; ++k)
            qv[h][k] = *(const float4*)&qtb[h * 768 + 4 * lane + 256 * k];

    // ---- pass 1: scores ----
    for (int t = w; t < 128; t += 4) {
        float4 x[3];
        #pragma unroll
        for (int k = 0; k < 3; ++k)
            x[k] = *(const float4*)&tfb[t * 768 + 4 * lane + 256 * k];
        float s[8];
        #pragma unroll
        for (int h = 0; h < 8; ++h) {
            s[h] = 0.f;
            #pragma unroll
            for (int k = 0; k < 3; ++k)
                s[h] += qv[h][k].x * x[k].x + qv[h][k].y * x[k].y +
                        qv[h][k].z * x[k].z + qv[h][k].w * x[k].w;
        }
        #pragma unroll
        for (int h = 0; h < 8; ++h)
            #pragma unroll
            for (int off = 32; off; off >>= 1)
                s[h] += __shfl_xor(s[h], off);
        if (lane == 0) {
            #pragma unroll
            for (int h = 0; h < 8; ++h) s_sc[h][t] = s[h];
        }
    }
    __syncthreads();

    // ---- mask + softmax over T: wave w handles heads 2w, 2w+1 ----
    int m0 = att[b * 128 + lane];
    int m1 = att[b * 128 + 64 + lane];
    #pragma unroll
    for (int hh = 0; hh < 2; ++hh) {
        int h = 2 * w + hh;
        float x0 = m0 ? s_sc[h][lane]      : -INFINITY;
        float x1 = m1 ? s_sc[h][lane + 64] : -INFINITY;
        float mx = fmaxf(x0, x1);
        #pragma unroll
        for (int off = 32; off; off >>= 1)
            mx = fmaxf(mx, __shfl_xor(mx, off));
        float e0 = m0 ? __expf(x0 - mx) : 0.f;
        float e1 = m1 ? __expf(x1 - mx) : 0.f;
        float sm = e0 + e1;
        #pragma unroll
        for (int off = 32; off; off >>= 1)
            sm += __shfl_xor(sm, off);
        float inv = 1.f / sm;
        s_sc[h][lane]      = e0 * inv;
        s_sc[h][lane + 64] = e1 * inv;
    }
    __syncthreads();

    // ---- pass 2: ctxtf accumulation, wave owns heads 2w, 2w+1 ----
    int h0 = 2 * w;
    float4 acc[2][3] = {};
    for (int t = 0; t < 128; ++t) {
        float4 x[3];
        #pragma unroll
        for (int k = 0; k < 3; ++k)
            x[k] = *(const float4*)&tfb[t * 768 + 4 * lane + 256 * k];
        float a0 = s_sc[h0][t];
        float a1 = s_sc[h0 + 1][t];
        #pragma unroll
        for (int k = 0; k < 3; ++k) {
            acc[0][k].x += a0 * x[k].x; acc[0][k].y += a0 * x[k].y;
            acc[0][k].z += a0 * x[k].z; acc[0][k].w += a0 * x[k].w;
            acc[1][k].x += a1 * x[k].x; acc[1][k].y += a1 * x[k].y;
            acc[1][k].z += a1 * x[k].z; acc[1][k].w += a1 * x[k].w;
        }
    }
    #pragma unroll
    for (int j = 0; j < 2; ++j)
        #pragma unroll
        for (int k = 0; k < 3; ++k)
            *(float4*)&ctxtf[(size_t)b * 6144 + (h0 + j) * 768 + 4 * lane + 256 * k] = acc[j][k];
}

// ======================================================================
// launch
// ======================================================================
extern "C" void kernel_launch(void* const* d_in, const int* in_sizes, int n_in,
                              void* d_out, int out_size, void* d_ws, size_t ws_size,
                              hipStream_t stream)
{
    const float* x    = (const float*)d_in[0];
    const float* zc   = (const float*)d_in[1];
    const float* tf   = (const float*)d_in[2];
    const int*   att  = (const int*)d_in[3];
    const float* Wg   = (const float*)d_in[4];
    const float* bg   = (const float*)d_in[5];
    const float* Wb   = (const float*)d_in[6];
    const float* bb   = (const float*)d_in[7];
    const float* Wl   = (const float*)d_in[8];
    const float* bl   = (const float*)d_in[9];
    const float* ln1g = (const float*)d_in[10];
    const float* ln1b = (const float*)d_in[11];
    const float* Wq   = (const float*)d_in[12];
    const float* bq   = (const float*)d_in[13];
    const float* Wk   = (const float*)d_in[14];
    // d_in[15] = bk: softmax-shift-invariant, cancels exactly.
    const float* Wv   = (const float*)d_in[16];
    const float* bv   = (const float*)d_in[17];
    const float* Wo   = (const float*)d_in[18];
    const float* bo   = (const float*)d_in[19];
    const float* ln2g = (const float*)d_in[20];
    const float* ln2b = (const float*)d_in[21];

    float* ws = (float*)d_ws;
    const size_t M1 = 1u << 20;
    float* OUT   = ws;            // [B,F] live to end
    float* H1    = ws + 1 * M1;   // [B,F]; reused as CTX
    float* GAM   = ws + 2 * M1;   // [B,F]; reused as AO
    float* BET   = ws + 3 * M1;   // [B,F]
    float* Q     = ws + 4 * M1;   // [B,F]
    float* QT    = ws + 5 * M1;   // [B,8,768] (6M)
    float* CTXTF = ws + 11 * M1;  // [B,8,768] (6M)
    float* CTX   = H1;
    float* AO    = GAM;

    // bf16 weight copies
    ushort* wb16 = (ushort*)(ws + 18 * M1);
    ushort* WlB = wb16;                          // 1M
    ushort* WqB = wb16 + 1 * M1;                 // 1M
    ushort* WoB = wb16 + 2 * M1;                 // 1M
    ushort* WgB = wb16 + 3 * M1;                 // 256K
    ushort* WbB = wb16 + 3 * M1 + 262144;        // 256K
    ushort* WvB = wb16 + 3 * M1 + 524288;        // 768K
    ushort* WkT = wb16 + 3 * M1 + 524288 + 786432; // 8*768*128

    dim3 blk(256);

    // ---- prep: weight conversions ----
    cvt_bf16<<<dim3(1024), blk, 0, stream>>>(Wl, WlB, 1048576);
    cvt_bf16<<<dim3(1024), blk, 0, stream>>>(Wq, WqB, 1048576);
    cvt_bf16<<<dim3(1024), blk, 0, stream>>>(Wo, WoB, 1048576);
    cvt_bf16<<<dim3(256),  blk, 0, stream>>>(Wg, WgB, 262144);
    cvt_bf16<<<dim3(256),  blk, 0, stream>>>(Wb, WbB, 262144);
    cvt_bf16<<<dim3(768),  blk, 0, stream>>>(Wv, WvB, 786432);
    transpose_wk<<<dim3(24, 4, 8), blk, 0, stream>>>(Wk, WkT);

    // ---- h1 = x @ Wl^T + bl ----
    gemm_nt_mfma<<<dim3(16, 16, 1), blk, 0, stream>>>(x, 1024, 0, WlB, 1024, 0,
        H1, 1024, 0, bl, 0, 1.f, 1024);
    // ---- gamma = z @ Wg^T + bg ; beta = z @ Wb^T + bb ----
    gemm_nt_mfma<<<dim3(16, 16, 1), blk, 0, stream>>>(zc, 256, 0, WgB, 256, 0,
        GAM, 1024, 0, bg, 0, 1.f, 256);
    gemm_nt_mfma<<<dim3(16, 16, 1), blk, 0, stream>>>(zc, 256, 0, WbB, 256, 0,
        BET, 1024, 0, bb, 0, 1.f, 256);
    // ---- out = LN(h1)*(1+gamma)+beta ----
    rowops1<<<dim3(1024), blk, 0, stream>>>(H1, GAM, BET, ln1g, ln1b, OUT);
    // ---- q = out @ Wq^T + bq ----
    gemm_nt_mfma<<<dim3(16, 16, 1), blk, 0, stream>>>(OUT, 1024, 0, WqB, 1024, 0,
        Q, 1024, 0, bq, 0, 1.f, 1024);
    // ---- qt[b,h,:] = (1/sqrt(128)) * q[b,h,:] @ Wk_h  (NT vs WkT) ----
    gemm_nt_mfma<<<dim3(12, 16, 8), blk, 0, stream>>>(Q, 1024, 128, WkT, 128, 98304,
        QT, 6144, 768, nullptr, 0, 0.08838834764831845f, 128);
    // ---- scores/softmax/weighted text features ----
    attn_kernel<<<dim3(1024), blk, 0, stream>>>(tf, QT, att, CTXTF);
    // ---- ctx = ctxtf @ Wv_h^T + bv  (batched over h) ----
    gemm_nt_mfma<<<dim3(2, 16, 8), blk, 0, stream>>>(CTXTF, 6144, 768, WvB, 768, 98304,
        CTX, 1024, 128, bv, 128, 1.f, 768);
    // ---- attn_out = ctx @ Wo^T + bo ----
    gemm_nt_mfma<<<dim3(16, 16, 1), blk, 0, stream>>>(CTX, 1024, 0, WoB, 1024, 0,
        AO, 1024, 0, bo, 0, 1.f, 1024);
    // ---- final = gelu(out + LN(attn_out)) ----
    rowops2<<<dim3(1024), blk, 0, stream>>>(OUT, AO, ln2g, ln2b, (float*)d_out);
}

// Round 5
// 709.048 us; speedup vs baseline: 1.3485x; 1.1110x over previous
//
#include <hip/hip_runtime.h>

// B=1024, T=128, F=1024, Z=256, TXT=768, H=8, d=128
#define EPS 1e-5f

typedef __bf16 bf16x8 __attribute__((ext_vector_type(8)));
typedef float f32x4 __attribute__((ext_vector_type(4)));
typedef ushort ushort8 __attribute__((ext_vector_type(8)));

static __device__ __forceinline__ ushort f2bf(float x) {
    union { float f; unsigned u; } v; v.f = x;
    unsigned r = v.u + 0x7fffu + ((v.u >> 16) & 1u);  // RNE
    return (ushort)(r >> 16);
}
static __device__ __forceinline__ float bf2f(ushort u) {
    union { unsigned u32; float f; } v; v.u32 = (unsigned)u << 16;
    return v.f;
}

// ======================================================================
// MFMA GEMM (NT): C = scale * (A_f32 @ W_bf16^T) + bias
// Tile 64x64, BK=64, 4 waves (2x2), 2x2 16x16x32 frags per wave.
// ======================================================================
__global__ __launch_bounds__(256)
void gemm_nt_mfma(const float* __restrict__ A, int lda, int Aoffz,
                  const ushort* __restrict__ W, int ldw, int Woffz,
                  float* __restrict__ C, int ldc, int Coffz,
                  const float* __restrict__ bias, int boffz,
                  float scale, int K)
{
    const int z = blockIdx.z;
    A += (size_t)z * Aoffz;
    W += (size_t)z * Woffz;
    C += (size_t)z * Coffz;
    const int bm = blockIdx.y * 64, bn = blockIdx.x * 64;

    __shared__ ushort As[64][72];
    __shared__ ushort Bs[64][72];

    const int tid  = threadIdx.x;
    const int lane = tid & 63, wv = tid >> 6;
    const int wm = (wv >> 1) * 32, wn = (wv & 1) * 32;

    const int srow = tid >> 2;
    const int scol = (tid & 3) * 16;
    const float*  Agp = A + (size_t)(bm + srow) * lda + scol;
    const ushort* Wgp = W + (size_t)(bn + srow) * ldw + scol;

    const int fr = lane & 15, fk = (lane >> 4) * 8;

    f32x4 acc[2][2] = {};

    for (int kt = 0; kt < K; kt += 64) {
        f32x4 a0 = *(const f32x4*)(Agp + kt + 0);
        f32x4 a1 = *(const f32x4*)(Agp + kt + 4);
        f32x4 a2 = *(const f32x4*)(Agp + kt + 8);
        f32x4 a3 = *(const f32x4*)(Agp + kt + 12);
        ushort8 b0 = *(const ushort8*)(Wgp + kt);
        ushort8 b1 = *(const ushort8*)(Wgp + kt + 8);

        ushort8 u0, u1;
        u0[0]=f2bf(a0[0]); u0[1]=f2bf(a0[1]); u0[2]=f2bf(a0[2]); u0[3]=f2bf(a0[3]);
        u0[4]=f2bf(a1[0]); u0[5]=f2bf(a1[1]); u0[6]=f2bf(a1[2]); u0[7]=f2bf(a1[3]);
        u1[0]=f2bf(a2[0]); u1[1]=f2bf(a2[1]); u1[2]=f2bf(a2[2]); u1[3]=f2bf(a2[3]);
        u1[4]=f2bf(a3[0]); u1[5]=f2bf(a3[1]); u1[6]=f2bf(a3[2]); u1[7]=f2bf(a3[3]);

        *(ushort8*)&As[srow][scol]     = u0;
        *(ushort8*)&As[srow][scol + 8] = u1;
        *(ushort8*)&Bs[srow][scol]     = b0;
        *(ushort8*)&Bs[srow][scol + 8] = b1;
        __syncthreads();

        #pragma unroll
        for (int ks = 0; ks < 64; ks += 32) {
            bf16x8 af0 = *(const bf16x8*)&As[wm + fr][ks + fk];
            bf16x8 af1 = *(const bf16x8*)&As[wm + 16 + fr][ks + fk];
            bf16x8 bf0 = *(const bf16x8*)&Bs[wn + fr][ks + fk];
            bf16x8 bf1 = *(const bf16x8*)&Bs[wn + 16 + fr][ks + fk];
            acc[0][0] = __builtin_amdgcn_mfma_f32_16x16x32_bf16(af0, bf0, acc[0][0], 0, 0, 0);
            acc[0][1] = __builtin_amdgcn_mfma_f32_16x16x32_bf16(af0, bf1, acc[0][1], 0, 0, 0);
            acc[1][0] = __builtin_amdgcn_mfma_f32_16x16x32_bf16(af1, bf0, acc[1][0], 0, 0, 0);
            acc[1][1] = __builtin_amdgcn_mfma_f32_16x16x32_bf16(af1, bf1, acc[1][1], 0, 0, 0);
        }
        __syncthreads();
    }

    const int rbase = (lane >> 4) * 4;
    #pragma unroll
    for (int mi = 0; mi < 2; ++mi) {
        #pragma unroll
        for (int ni = 0; ni < 2; ++ni) {
            const int col = bn + wn + ni * 16 + fr;
            const float bvv = bias ? (bias + (size_t)z * boffz)[col] : 0.f;
            #pragma unroll
            for (int r = 0; r < 4; ++r) {
                const int row = bm + wm + mi * 16 + rbase + r;
                C[(size_t)row * ldc + col] = acc[mi][ni][r] * scale + bvv;
            }
        }
    }
}

// ======================================================================
// cvt_all: all weight f32->bf16 conversions in ONE kernel.
// Segments (in float4 units): Wl 262144 | Wq 262144 | Wo 262144 |
// Wv 196608 | Wg 65536 | Wb 65536.  Also copies bg|bb -> bgb (f32[2048]).
// Grid: 4352 x 256.
// ======================================================================
__global__ __launch_bounds__(256)
void cvt_all(const float* __restrict__ Wl, const float* __restrict__ Wq,
             const float* __restrict__ Wo, const float* __restrict__ Wv,
             const float* __restrict__ Wg, const float* __restrict__ Wb,
             const float* __restrict__ bg, const float* __restrict__ bb,
             ushort* __restrict__ WlB, ushort* __restrict__ WqB,
             ushort* __restrict__ WoB, ushort* __restrict__ WvB,
             ushort* __restrict__ WgbB, float* __restrict__ bgb)
{
    int gid = blockIdx.x * 256 + threadIdx.x;
    if (gid < 512) {  // bgb: 2048 f32 = 512 float4
        f32x4 v = (gid < 256) ? *(const f32x4*)(bg + gid * 4)
                              : *(const f32x4*)(bb + (gid - 256) * 4);
        *(f32x4*)(bgb + gid * 4) = v;
    }
    const float* src; ushort* dst; int off;
    if      (gid <  262144) { src = Wl; dst = WlB;           off = gid;          }
    else if (gid <  524288) { src = Wq; dst = WqB;           off = gid - 262144; }
    else if (gid <  786432) { src = Wo; dst = WoB;           off = gid - 524288; }
    else if (gid <  983040) { src = Wv; dst = WvB;           off = gid - 786432; }
    else if (gid < 1048576) { src = Wg; dst = WgbB;          off = gid - 983040; }
    else if (gid < 1114112) { src = Wb; dst = WgbB + 262144; off = gid - 1048576;}
    else return;
    f32x4 v = *(const f32x4*)(src + (size_t)off * 4);
    ushort4 o;
    o.x = f2bf(v[0]); o.y = f2bf(v[1]); o.z = f2bf(v[2]); o.w = f2bf(v[3]);
    *(ushort4*)(dst + (size_t)off * 4) = o;
}

// ======================================================================
// transpose_wk: Wk [1024,768] f32 -> WkT [8][768][128] bf16
// ======================================================================
__global__ __launch_bounds__(256)
void transpose_wk(const float* __restrict__ Wk, ushort* __restrict__ WkT)
{
    __shared__ ushort s[32][33];
    const int h  = blockIdx.z;
    const int c0 = blockIdx.x * 32, d0 = blockIdx.y * 32;
    const int tx = threadIdx.x & 31, ty = threadIdx.x >> 5;
    #pragma unroll
    for (int i = 0; i < 4; ++i) {
        int d = d0 + ty + i * 8;
        s[ty + i * 8][tx] = f2bf(Wk[(size_t)(h * 128 + d) * 768 + c0 + tx]);
    }
    __syncthreads();
    #pragma unroll
    for (int i = 0; i < 4; ++i) {
        int c = c0 + ty + i * 8;
        WkT[((size_t)h * 768 + c) * 128 + d0 + tx] = s[tx][ty + i * 8];
    }
}

// ======================================================================
// block reduce (2 values, 256 thr)
// ======================================================================
__device__ inline void block_reduce2(float& a, float& b, float* sred)
{
    #pragma unroll
    for (int off = 32; off; off >>= 1) {
        a += __shfl_xor(a, off);
        b += __shfl_xor(b, off);
    }
    int w = threadIdx.x >> 6, lane = threadIdx.x & 63;
    if (lane == 0) { sred[w * 2] = a; sred[w * 2 + 1] = b; }
    __syncthreads();
    a = sred[0] + sred[2] + sred[4] + sred[6];
    b = sred[1] + sred[3] + sred[5] + sred[7];
}

// ======================================================================
// rowops1: out = LN(h1)*g+b then FiLM.  gamma|beta packed in GB [B,2048].
// ======================================================================
__global__ __launch_bounds__(256)
void rowops1(const float* __restrict__ h1, const float* __restrict__ gb,
             const float* __restrict__ g, const float* __restrict__ bta,
             float* __restrict__ out)
{
    __shared__ float sred[8];
    int b = blockIdx.x, tid = threadIdx.x;
    const float4 v = ((const float4*)(h1 + (size_t)b * 1024))[tid];
    float s  = v.x + v.y + v.z + v.w;
    float ss = v.x * v.x + v.y * v.y + v.z * v.z + v.w * v.w;
    block_reduce2(s, ss, sred);
    float mu  = s * (1.f / 1024.f);
    float var = ss * (1.f / 1024.f) - mu * mu;
    float rs  = rsqrtf(var + EPS);
    float4 gv = ((const float4*)g)[tid];
    float4 bv = ((const float4*)bta)[tid];
    float4 ga = ((const float4*)(gb + (size_t)b * 2048))[tid];
    float4 be = ((const float4*)(gb + (size_t)b * 2048 + 1024))[tid];
    float4 o;
    o.x = ((v.x - mu) * rs * gv.x + bv.x) * (1.f + ga.x) + be.x;
    o.y = ((v.y - mu) * rs * gv.y + bv.y) * (1.f + ga.y) + be.y;
    o.z = ((v.z - mu) * rs * gv.z + bv.z) * (1.f + ga.z) + be.z;
    o.w = ((v.w - mu) * rs * gv.w + bv.w) * (1.f + ga.w) + be.w;
    ((float4*)(out + (size_t)b * 1024))[tid] = o;
}

// ======================================================================
// rowops2: final = gelu(out + LN(attn_out)*g+b)
// ======================================================================
__global__ __launch_bounds__(256)
void rowops2(const float* __restrict__ outp, const float* __restrict__ ao,
             const float* __restrict__ g, const float* __restrict__ bta,
             float* __restrict__ dst)
{
    __shared__ float sred[8];
    int b = blockIdx.x, tid = threadIdx.x;
    const float4 v = ((const float4*)(ao + (size_t)b * 1024))[tid];
    float s  = v.x + v.y + v.z + v.w;
    float ss = v.x * v.x + v.y * v.y + v.z * v.z + v.w * v.w;
    block_reduce2(s, ss, sred);
    float mu  = s * (1.f / 1024.f);
    float var = ss * (1.f / 1024.f) - mu * mu;
    float rs  = rsqrtf(var + EPS);
    float4 gv = ((const float4*)g)[tid];
    float4 bv = ((const float4*)bta)[tid];
    float4 ov = ((const float4*)(outp + (size_t)b * 1024))[tid];
    float y0 = ov.x + ((v.x - mu) * rs * gv.x + bv.x);
    float y1 = ov.y + ((v.y - mu) * rs * gv.y + bv.y);
    float y2 = ov.z + ((v.z - mu) * rs * gv.z + bv.z);
    float y3 = ov.w + ((v.w - mu) * rs * gv.w + bv.w);
    float4 o;
    o.x = 0.5f * y0 * (1.f + erff(y0 * 0.70710678118654752f));
    o.y = 0.5f * y1 * (1.f + erff(y1 * 0.70710678118654752f));
    o.z = 0.5f * y2 * (1.f + erff(y2 * 0.70710678118654752f));
    o.w = 0.5f * y3 * (1.f + erff(y3 * 0.70710678118654752f));
    ((float4*)(dst + (size_t)b * 1024))[tid] = o;
}

// ======================================================================
// attn_fused: ONE pass over tf.  Per block b (256 thr = 4 waves):
//   - stage qt[b] (8x768, pre-scaled by 1/sqrt(d)) as bf16 in LDS,
//     zero-padded to 16 rows (MFMA A operand).
//   - 4 stages of 32 t-rows: stage tf tile bf16 -> LDS; waves 0/1 compute
//     scores for their 16-row subtile via 24x mfma_16x16x32_bf16 (K=768);
//     each wave owns 2 heads: online softmax (running m, sum) + rescale +
//     VALU PV accumulation from the SAME LDS tile.
//   - normalize, write ctxtf[b] (8x768 f32).
// tf read exactly once (402 MB total). LDS ~76.5 KB -> 2 blocks/CU.
// ======================================================================
__global__ __launch_bounds__(256)
void attn_fused(const float* __restrict__ tf, const float* __restrict__ qt,
                const int* __restrict__ att, float* __restrict__ ctxtf)
{
    const int b = blockIdx.x;
    const int tid = threadIdx.x, lane = tid & 63, wv = tid >> 6;

    __shared__ ushort qtS[16][776];
    __shared__ ushort TF[32][776];
    __shared__ float s_sc[8][32];
    __shared__ float ps[8][32];

    const float* tfb = tf + (size_t)b * 98304;
    const float* qtb = qt + (size_t)b * 6144;

    // ---- stage qt rows 0-7 (bf16), zero rows 8-15 ----
    {
        const int r  = tid >> 5;             // 0..7
        const int c0 = (tid & 31) * 24;      // 24 cols per thread
        #pragma unroll
        for (int j = 0; j < 6; ++j) {
            f32x4 v = *(const f32x4*)&qtb[r * 768 + c0 + 4 * j];
            ushort4 o;
            o.x = f2bf(v[0]); o.y = f2bf(v[1]); o.z = f2bf(v[2]); o.w = f2bf(v[3]);
            *(ushort4*)&qtS[r][c0 + 4 * j] = o;
        }
        const ushort4 z4 = {0, 0, 0, 0};
        #pragma unroll
        for (int j = 0; j < 6; ++j)
            *(ushort4*)&qtS[8 + r][c0 + 4 * j] = z4;
    }

    float acc[2][3][4] = {};
    float mrun = -INFINITY, srun = 0.f;
    const int fr = lane & 15, fko = (lane >> 4) * 8;
    const int hloc = lane >> 5, tl = lane & 31;
    const int h_own = 2 * wv + hloc;
    const int h0 = 2 * wv;

    for (int s = 0; s < 4; ++s) {
        __syncthreads();   // prev stage PV done with TF (covers qtS at s=0)
        // ---- stage TF rows [32s, 32s+32) as bf16 ----
        {
            const int r  = tid >> 3;             // 0..31
            const int c0 = (tid & 7) * 96;
            const float* srcr = tfb + (size_t)(s * 32 + r) * 768 + c0;
            #pragma unroll
            for (int j = 0; j < 24; ++j) {
                f32x4 v = *(const f32x4*)(srcr + 4 * j);
                ushort4 o;
                o.x = f2bf(v[0]); o.y = f2bf(v[1]); o.z = f2bf(v[2]); o.w = f2bf(v[3]);
                *(ushort4*)&TF[r][c0 + 4 * j] = o;
            }
        }
        __syncthreads();   // TF (and qtS) ready
        // ---- scores: waves 0,1 -> s_sc[h][0..31] ----
        if (wv < 2) {
            f32x4 sacc = {0.f, 0.f, 0.f, 0.f};
            #pragma unroll
            for (int ks = 0; ks < 768; ks += 32) {
                bf16x8 aq = *(const bf16x8*)&qtS[fr][ks + fko];
                bf16x8 bt = *(const bf16x8*)&TF[wv * 16 + fr][ks + fko];
                sacc = __builtin_amdgcn_mfma_f32_16x16x32_bf16(aq, bt, sacc, 0, 0, 0);
            }
            if (lane < 32) {
                const int hbase = (lane >> 4) * 4;
                #pragma unroll
                for (int r = 0; r < 4; ++r)
                    s_sc[hbase + r][wv * 16 + (lane & 15)] = sacc[r];
            }
        }
        __syncthreads();   // scores ready
        // ---- online softmax: wave owns heads 2wv (lanes 0-31), 2wv+1 (32-63) ----
        {
            const int mask = att[b * 128 + s * 32 + tl];
            float sv = mask ? s_sc[h_own][tl] : -INFINITY;
            float mx = sv;
            mx = fmaxf(mx, __shfl_xor(mx, 16));
            mx = fmaxf(mx, __shfl_xor(mx, 8));
            mx = fmaxf(mx, __shfl_xor(mx, 4));
            mx = fmaxf(mx, __shfl_xor(mx, 2));
            mx = fmaxf(mx, __shfl_xor(mx, 1));
            float mnew = fmaxf(mrun, mx);
            float p = mask ? __expf(sv - mnew) : 0.f;
            float f = (mnew == -INFINITY) ? 1.f : __expf(mrun - mnew);
            float psum = p;
            psum += __shfl_xor(psum, 16);
            psum += __shfl_xor(psum, 8);
            psum += __shfl_xor(psum, 4);
            psum += __shfl_xor(psum, 2);
            psum += __shfl_xor(psum, 1);
            srun = srun * f + psum;
            mrun = mnew;
            ps[h_own][tl] = p;
            const float f0 = __shfl(f, 0);
            const float f1 = __shfl(f, 32);
            #pragma unroll
            for (int k = 0; k < 3; ++k)
                #pragma unroll
                for (int e = 0; e < 4; ++e) {
                    acc[0][k][e] *= f0;
                    acc[1][k][e] *= f1;
                }
        }
        // ---- PV: accumulate weighted tf rows (same-wave ps, no barrier) ----
        {
            #pragma unroll 8
            for (int t = 0; t < 32; ++t) {
                const float p0 = ps[h0][t];
                const float p1 = ps[h0 + 1][t];
                #pragma unroll
                for (int k = 0; k < 3; ++k) {
                    ushort4 u = *(const ushort4*)&TF[t][4 * lane + 256 * k];
                    float x0 = bf2f(u.x), x1 = bf2f(u.y), x2 = bf2f(u.z), x3 = bf2f(u.w);
                    acc[0][k][0] += p0 * x0; acc[0][k][1] += p0 * x1;
                    acc[0][k][2] += p0 * x2; acc[0][k][3] += p0 * x3;
                    acc[1][k][0] += p1 * x0; acc[1][k][1] += p1 * x1;
                    acc[1][k][2] += p1 * x2; acc[1][k][3] += p1 * x3;
                }
            }
        }
    }

    // ---- normalize + write ----
    const float sum0 = __shfl(srun, 0);
    const float sum1 = __shfl(srun, 32);
    const float i0 = 1.f / sum0, i1 = 1.f / sum1;
    #pragma unroll
    for (int k = 0; k < 3; ++k) {
        f32x4 o0, o1;
        #pragma unroll
        for (int e = 0; e < 4; ++e) {
            o0[e] = acc[0][k][e] * i0;
            o1[e] = acc[1][k][e] * i1;
        }
        *(f32x4*)&ctxtf[(size_t)b * 6144 + (size_t)h0 * 768 + 4 * lane + 256 * k] = o0;
        *(f32x4*)&ctxtf[(size_t)b * 6144 + (size_t)(h0 + 1) * 768 + 4 * lane + 256 * k] = o1;
    }
}

// ======================================================================
// launch
// ======================================================================
extern "C" void kernel_launch(void* const* d_in, const int* in_sizes, int n_in,
                              void* d_out, int out_size, void* d_ws, size_t ws_size,
                              hipStream_t stream)
{
    const float* x    = (const float*)d_in[0];
    const float* zc   = (const float*)d_in[1];
    const float* tf   = (const float*)d_in[2];
    const int*   att  = (const int*)d_in[3];
    const float* Wg   = (const float*)d_in[4];
    const float* bg   = (const float*)d_in[5];
    const float* Wb   = (const float*)d_in[6];
    const float* bb   = (const float*)d_in[7];
    const float* Wl   = (const float*)d_in[8];
    const float* bl   = (const float*)d_in[9];
    const float* ln1g = (const float*)d_in[10];
    const float* ln1b = (const float*)d_in[11];
    const float* Wq   = (const float*)d_in[12];
    const float* bq   = (const float*)d_in[13];
    const float* Wk   = (const float*)d_in[14];
    // d_in[15] = bk: softmax-shift-invariant, cancels exactly.
    const float* Wv   = (const float*)d_in[16];
    const float* bv   = (const float*)d_in[17];
    const float* Wo   = (const float*)d_in[18];
    const float* bo   = (const float*)d_in[19];
    const float* ln2g = (const float*)d_in[20];
    const float* ln2b = (const float*)d_in[21];

    float* ws = (float*)d_ws;
    const size_t M1 = 1u << 20;
    float* OUT   = ws;            // [B,F] live to end
    float* H1    = ws + 1 * M1;   // [B,F]; reused as CTX
    float* GB    = ws + 2 * M1;   // [B,2048] gamma|beta
    float* Q     = ws + 4 * M1;   // [B,F]
    float* QT    = ws + 5 * M1;   // [B,8,768] (6M)
    float* CTXTF = ws + 11 * M1;  // [B,8,768] (6M)
    float* AO    = ws + 17 * M1;  // [B,F]
    float* bgb   = ws + 18 * M1;  // [2048] bg|bb
    float* CTX   = H1;

    ushort* wb16 = (ushort*)(ws + 19 * M1);
    ushort* WlB  = wb16;                       // 1M
    ushort* WqB  = wb16 + 1 * M1;              // 1M
    ushort* WoB  = wb16 + 2 * M1;              // 1M
    ushort* WvB  = wb16 + 3 * M1;              // 768K
    ushort* WgbB = wb16 + 3 * M1 + 786432;     // 512K  [Wg|Wb][2048,256]
    ushort* WkT  = wb16 + 3 * M1 + 786432 + 524288;  // 768K [8][768][128]

    dim3 blk(256);

    // ---- prep (2 dispatches) ----
    cvt_all<<<dim3(4352), blk, 0, stream>>>(Wl, Wq, Wo, Wv, Wg, Wb, bg, bb,
                                            WlB, WqB, WoB, WvB, WgbB, bgb);
    transpose_wk<<<dim3(24, 4, 8), blk, 0, stream>>>(Wk, WkT);

    // ---- h1 = x @ Wl^T + bl ----
    gemm_nt_mfma<<<dim3(16, 16, 1), blk, 0, stream>>>(x, 1024, 0, WlB, 1024, 0,
        H1, 1024, 0, bl, 0, 1.f, 1024);
    // ---- [gamma|beta] = z @ [Wg|Wb]^T + [bg|bb]  (one N=2048 GEMM) ----
    gemm_nt_mfma<<<dim3(32, 16, 1), blk, 0, stream>>>(zc, 256, 0, WgbB, 256, 0,
        GB, 2048, 0, bgb, 0, 1.f, 256);
    // ---- out = LN(h1)*(1+gamma)+beta ----
    rowops1<<<dim3(1024), blk, 0, stream>>>(H1, GB, ln1g, ln1b, OUT);
    // ---- q = out @ Wq^T + bq ----
    gemm_nt_mfma<<<dim3(16, 16, 1), blk, 0, stream>>>(OUT, 1024, 0, WqB, 1024, 0,
        Q, 1024, 0, bq, 0, 1.f, 1024);
    // ---- qt[b,h,:] = (1/sqrt(128)) * q[b,h,:] @ Wk_h ----
    gemm_nt_mfma<<<dim3(12, 16, 8), blk, 0, stream>>>(Q, 1024, 128, WkT, 128, 98304,
        QT, 6144, 768, nullptr, 0, 0.08838834764831845f, 128);
    // ---- fused single-pass attention ----
    attn_fused<<<dim3(1024), blk, 0, stream>>>(tf, QT, att, CTXTF);
    // ---- ctx = ctxtf @ Wv_h^T + bv ----
    gemm_nt_mfma<<<dim3(2, 16, 8), blk, 0, stream>>>(CTXTF, 6144, 768, WvB, 768, 98304,
        CTX, 1024, 128, bv, 128, 1.f, 768);
    // ---- attn_out = ctx @ Wo^T + bo ----
    gemm_nt_mfma<<<dim3(16, 16, 1), blk, 0, stream>>>(CTX, 1024, 0, WoB, 1024, 0,
        AO, 1024, 0, bo, 0, 1.f, 1024);
    // ---- final = gelu(out + LN(attn_out)) ----
    rowops2<<<dim3(1024), blk, 0, stream>>>(OUT, AO, ln2g, ln2b, (float*)d_out);
}

// Round 6
// 673.770 us; speedup vs baseline: 1.4191x; 1.0524x over previous
//
#include <hip/hip_runtime.h>

// B=1024, T=128, F=1024, Z=256, TXT=768, H=8, d=128
#define EPS 1e-5f

typedef __bf16 bf16x8 __attribute__((ext_vector_type(8)));
typedef float f32x4 __attribute__((ext_vector_type(4)));
typedef ushort ushort8 __attribute__((ext_vector_type(8)));

static __device__ __forceinline__ ushort f2bf(float x) {
    union { float f; unsigned u; } v; v.f = x;
    unsigned r = v.u + 0x7fffu + ((v.u >> 16) & 1u);  // RNE
    return (ushort)(r >> 16);
}
static __device__ __forceinline__ float bf2f(ushort u) {
    union { unsigned u32; float f; } v; v.u32 = (unsigned)u << 16;
    return v.f;
}

// ======================================================================
// gemm_bb: C = scale * (A_bf16 @ W_bf16^T) + bias(f32)
//   A: [M,K] bf16 row-major (+ z*Aoffz), W: [N,K] bf16 (+ z*Woffz)
//   C: f32 or bf16 per OB template (+ z*Coffz elements)
// Tile 64x64, BK=64, 4 waves (2x2 of 32x32), 2x2 16x16x32 frags.
// Register-prefetch pipeline: tile kt+1 loads issued during tile kt MFMA.
// LDS rows padded to 72 (2-way bank aliasing only = free).
// ======================================================================
template<int OB>
__global__ __launch_bounds__(256)
void gemm_bb(const ushort* __restrict__ A, int lda, int Aoffz,
             const ushort* __restrict__ W, int ldw, int Woffz,
             void* __restrict__ Cv, int ldc, int Coffz,
             const float* __restrict__ bias, int boffz,
             float scale, int K)
{
    const int z = blockIdx.z;
    A += (size_t)z * Aoffz;
    W += (size_t)z * Woffz;
    const int bm = blockIdx.y * 64, bn = blockIdx.x * 64;

    __shared__ ushort As[64][72];
    __shared__ ushort Bs[64][72];

    const int tid  = threadIdx.x;
    const int lane = tid & 63, wv = tid >> 6;
    const int wm = (wv >> 1) * 32, wn = (wv & 1) * 32;

    const int srow = tid >> 2;
    const int scol = (tid & 3) * 16;
    const ushort* Agp = A + (size_t)(bm + srow) * lda + scol;
    const ushort* Wgp = W + (size_t)(bn + srow) * ldw + scol;

    const int fr = lane & 15, fk = (lane >> 4) * 8;

    f32x4 acc[2][2] = {};

    // prologue: prefetch tile 0
    ushort8 a0 = *(const ushort8*)(Agp);
    ushort8 a1 = *(const ushort8*)(Agp + 8);
    ushort8 b0 = *(const ushort8*)(Wgp);
    ushort8 b1 = *(const ushort8*)(Wgp + 8);

    for (int kt = 0; kt < K; kt += 64) {
        *(ushort8*)&As[srow][scol]     = a0;
        *(ushort8*)&As[srow][scol + 8] = a1;
        *(ushort8*)&Bs[srow][scol]     = b0;
        *(ushort8*)&Bs[srow][scol + 8] = b1;
        __syncthreads();
        if (kt + 64 < K) {   // prefetch next tile; lands during MFMA below
            a0 = *(const ushort8*)(Agp + kt + 64);
            a1 = *(const ushort8*)(Agp + kt + 64 + 8);
            b0 = *(const ushort8*)(Wgp + kt + 64);
            b1 = *(const ushort8*)(Wgp + kt + 64 + 8);
        }
        #pragma unroll
        for (int ks = 0; ks < 64; ks += 32) {
            bf16x8 af0 = *(const bf16x8*)&As[wm + fr][ks + fk];
            bf16x8 af1 = *(const bf16x8*)&As[wm + 16 + fr][ks + fk];
            bf16x8 bf0 = *(const bf16x8*)&Bs[wn + fr][ks + fk];
            bf16x8 bf1 = *(const bf16x8*)&Bs[wn + 16 + fr][ks + fk];
            acc[0][0] = __builtin_amdgcn_mfma_f32_16x16x32_bf16(af0, bf0, acc[0][0], 0, 0, 0);
            acc[0][1] = __builtin_amdgcn_mfma_f32_16x16x32_bf16(af0, bf1, acc[0][1], 0, 0, 0);
            acc[1][0] = __builtin_amdgcn_mfma_f32_16x16x32_bf16(af1, bf0, acc[1][0], 0, 0, 0);
            acc[1][1] = __builtin_amdgcn_mfma_f32_16x16x32_bf16(af1, bf1, acc[1][1], 0, 0, 0);
        }
        __syncthreads();
    }

    const int rbase = (lane >> 4) * 4;
    #pragma unroll
    for (int mi = 0; mi < 2; ++mi) {
        #pragma unroll
        for (int ni = 0; ni < 2; ++ni) {
            const int col = bn + wn + ni * 16 + fr;
            const float bvv = bias ? (bias + (size_t)z * boffz)[col] : 0.f;
            #pragma unroll
            for (int r = 0; r < 4; ++r) {
                const int row = bm + wm + mi * 16 + rbase + r;
                const float val = acc[mi][ni][r] * scale + bvv;
                if (OB) {
                    ((ushort*)Cv)[(size_t)z * Coffz + (size_t)row * ldc + col] = f2bf(val);
                } else {
                    ((float*)Cv)[(size_t)z * Coffz + (size_t)row * ldc + col] = val;
                }
            }
        }
    }
}

// ======================================================================
// cvt_all: every f32->bf16 conversion in ONE kernel (weights + x + z),
// plus bg|bb -> bgb f32 copy.  Segments in float4 units; grid 5632 x 256.
// ======================================================================
__global__ __launch_bounds__(256)
void cvt_all(const float* __restrict__ Wl, const float* __restrict__ Wq,
             const float* __restrict__ Wo, const float* __restrict__ Wv,
             const float* __restrict__ Wg, const float* __restrict__ Wb,
             const float* __restrict__ x,  const float* __restrict__ zc,
             const float* __restrict__ bg, const float* __restrict__ bb,
             ushort* __restrict__ WlB, ushort* __restrict__ WqB,
             ushort* __restrict__ WoB, ushort* __restrict__ WvB,
             ushort* __restrict__ WgbB, ushort* __restrict__ xB,
             ushort* __restrict__ zB, float* __restrict__ bgb)
{
    int gid = blockIdx.x * 256 + threadIdx.x;
    if (gid < 512) {  // bgb: 2048 f32 = 512 float4
        f32x4 v = (gid < 256) ? *(const f32x4*)(bg + gid * 4)
                              : *(const f32x4*)(bb + (gid - 256) * 4);
        *(f32x4*)(bgb + gid * 4) = v;
    }
    const float* src; ushort* dst; int off;
    if      (gid <  262144) { src = Wl; dst = WlB;           off = gid;          }
    else if (gid <  524288) { src = Wq; dst = WqB;           off = gid - 262144; }
    else if (gid <  786432) { src = Wo; dst = WoB;           off = gid - 524288; }
    else if (gid <  983040) { src = Wv; dst = WvB;           off = gid - 786432; }
    else if (gid < 1048576) { src = Wg; dst = WgbB;          off = gid - 983040; }
    else if (gid < 1114112) { src = Wb; dst = WgbB + 262144; off = gid - 1048576;}
    else if (gid < 1376256) { src = x;  dst = xB;            off = gid - 1114112;}
    else if (gid < 1441792) { src = zc; dst = zB;            off = gid - 1376256;}
    else return;
    f32x4 v = *(const f32x4*)(src + (size_t)off * 4);
    ushort4 o;
    o.x = f2bf(v[0]); o.y = f2bf(v[1]); o.z = f2bf(v[2]); o.w = f2bf(v[3]);
    *(ushort4*)(dst + (size_t)off * 4) = o;
}

// ======================================================================
// transpose_wk: Wk [1024,768] f32 -> WkT [8][768][128] bf16
// ======================================================================
__global__ __launch_bounds__(256)
void transpose_wk(const float* __restrict__ Wk, ushort* __restrict__ WkT)
{
    __shared__ ushort s[32][33];
    const int h  = blockIdx.z;
    const int c0 = blockIdx.x * 32, d0 = blockIdx.y * 32;
    const int tx = threadIdx.x & 31, ty = threadIdx.x >> 5;
    #pragma unroll
    for (int i = 0; i < 4; ++i) {
        int d = d0 + ty + i * 8;
        s[ty + i * 8][tx] = f2bf(Wk[(size_t)(h * 128 + d) * 768 + c0 + tx]);
    }
    __syncthreads();
    #pragma unroll
    for (int i = 0; i < 4; ++i) {
        int c = c0 + ty + i * 8;
        WkT[((size_t)h * 768 + c) * 128 + d0 + tx] = s[tx][ty + i * 8];
    }
}

// ======================================================================
// block reduce (2 values, 256 thr)
// ======================================================================
__device__ inline void block_reduce2(float& a, float& b, float* sred)
{
    #pragma unroll
    for (int off = 32; off; off >>= 1) {
        a += __shfl_xor(a, off);
        b += __shfl_xor(b, off);
    }
    int w = threadIdx.x >> 6, lane = threadIdx.x & 63;
    if (lane == 0) { sred[w * 2] = a; sred[w * 2 + 1] = b; }
    __syncthreads();
    a = sred[0] + sred[2] + sred[4] + sred[6];
    b = sred[1] + sred[3] + sred[5] + sred[7];
}

// ======================================================================
// rowops1: outb(bf16) = LN(h1)*g+b then FiLM.  gamma|beta in GB [B,2048].
// ======================================================================
__global__ __launch_bounds__(256)
void rowops1(const float* __restrict__ h1, const float* __restrict__ gb,
             const float* __restrict__ g, const float* __restrict__ bta,
             ushort* __restrict__ outb)
{
    __shared__ float sred[8];
    int b = blockIdx.x, tid = threadIdx.x;
    const float4 v = ((const float4*)(h1 + (size_t)b * 1024))[tid];
    float s  = v.x + v.y + v.z + v.w;
    float ss = v.x * v.x + v.y * v.y + v.z * v.z + v.w * v.w;
    block_reduce2(s, ss, sred);
    float mu  = s * (1.f / 1024.f);
    float var = ss * (1.f / 1024.f) - mu * mu;
    float rs  = rsqrtf(var + EPS);
    float4 gv = ((const float4*)g)[tid];
    float4 bv = ((const float4*)bta)[tid];
    float4 ga = ((const float4*)(gb + (size_t)b * 2048))[tid];
    float4 be = ((const float4*)(gb + (size_t)b * 2048 + 1024))[tid];
    ushort4 o;
    o.x = f2bf(((v.x - mu) * rs * gv.x + bv.x) * (1.f + ga.x) + be.x);
    o.y = f2bf(((v.y - mu) * rs * gv.y + bv.y) * (1.f + ga.y) + be.y);
    o.z = f2bf(((v.z - mu) * rs * gv.z + bv.z) * (1.f + ga.z) + be.z);
    o.w = f2bf(((v.w - mu) * rs * gv.w + bv.w) * (1.f + ga.w) + be.w);
    ((ushort4*)(outb + (size_t)b * 1024))[tid] = o;
}

// ======================================================================
// rowops2: final = gelu(outb + LN(attn_out)*g+b)
// ======================================================================
__global__ __launch_bounds__(256)
void rowops2(const ushort* __restrict__ outb, const float* __restrict__ ao,
             const float* __restrict__ g, const float* __restrict__ bta,
             float* __restrict__ dst)
{
    __shared__ float sred[8];
    int b = blockIdx.x, tid = threadIdx.x;
    const float4 v = ((const float4*)(ao + (size_t)b * 1024))[tid];
    float s  = v.x + v.y + v.z + v.w;
    float ss = v.x * v.x + v.y * v.y + v.z * v.z + v.w * v.w;
    block_reduce2(s, ss, sred);
    float mu  = s * (1.f / 1024.f);
    float var = ss * (1.f / 1024.f) - mu * mu;
    float rs  = rsqrtf(var + EPS);
    float4 gv = ((const float4*)g)[tid];
    float4 bv = ((const float4*)bta)[tid];
    ushort4 ou = ((const ushort4*)(outb + (size_t)b * 1024))[tid];
    float y0 = bf2f(ou.x) + ((v.x - mu) * rs * gv.x + bv.x);
    float y1 = bf2f(ou.y) + ((v.y - mu) * rs * gv.y + bv.y);
    float y2 = bf2f(ou.z) + ((v.z - mu) * rs * gv.z + bv.z);
    float y3 = bf2f(ou.w) + ((v.w - mu) * rs * gv.w + bv.w);
    float4 o;
    o.x = 0.5f * y0 * (1.f + erff(y0 * 0.70710678118654752f));
    o.y = 0.5f * y1 * (1.f + erff(y1 * 0.70710678118654752f));
    o.z = 0.5f * y2 * (1.f + erff(y2 * 0.70710678118654752f));
    o.w = 0.5f * y3 * (1.f + erff(y3 * 0.70710678118654752f));
    ((float4*)(dst + (size_t)b * 1024))[tid] = o;
}

// ======================================================================
// attn_fused: ONE pass over tf.  qt now bf16 (copy staging), ctxtf bf16 out.
// 4 stages of 32 t-rows: stage tf bf16 -> LDS; waves 0/1 MFMA scores;
// online softmax per wave-owned head pair; VALU PV from same LDS tile.
// ======================================================================
__global__ __launch_bounds__(256)
void attn_fused(const float* __restrict__ tf, const ushort* __restrict__ qt,
                const int* __restrict__ att, ushort* __restrict__ ctxtf)
{
    const int b = blockIdx.x;
    const int tid = threadIdx.x, lane = tid & 63, wv = tid >> 6;

    __shared__ ushort qtS[16][776];
    __shared__ ushort TF[32][776];
    __shared__ float s_sc[8][32];
    __shared__ float ps[8][32];

    const float*  tfb = tf + (size_t)b * 98304;
    const ushort* qtb = qt + (size_t)b * 6144;

    // ---- stage qt rows 0-7 (bf16 copy), zero rows 8-15 ----
    {
        const int r  = tid >> 5;             // 0..7
        const int c0 = (tid & 31) * 24;      // 24 cols per thread
        #pragma unroll
        for (int j = 0; j < 3; ++j)
            *(ushort8*)&qtS[r][c0 + 8 * j] = *(const ushort8*)&qtb[r * 768 + c0 + 8 * j];
        const ushort8 z8 = {0,0,0,0,0,0,0,0};
        #pragma unroll
        for (int j = 0; j < 3; ++j)
            *(ushort8*)&qtS[8 + r][c0 + 8 * j] = z8;
    }

    float acc[2][3][4] = {};
    float mrun = -INFINITY, srun = 0.f;
    const int fr = lane & 15, fko = (lane >> 4) * 8;
    const int hloc = lane >> 5, tl = lane & 31;
    const int h_own = 2 * wv + hloc;
    const int h0 = 2 * wv;

    for (int s = 0; s < 4; ++s) {
        __syncthreads();   // prev stage PV done with TF (covers qtS at s=0)
        // ---- stage TF rows [32s, 32s+32) as bf16 ----
        {
            const int r  = tid >> 3;             // 0..31
            const int c0 = (tid & 7) * 96;
            const float* srcr = tfb + (size_t)(s * 32 + r) * 768 + c0;
            #pragma unroll
            for (int j = 0; j < 24; ++j) {
                f32x4 v = *(const f32x4*)(srcr + 4 * j);
                ushort4 o;
                o.x = f2bf(v[0]); o.y = f2bf(v[1]); o.z = f2bf(v[2]); o.w = f2bf(v[3]);
                *(ushort4*)&TF[r][c0 + 4 * j] = o;
            }
        }
        __syncthreads();   // TF (and qtS) ready
        // ---- scores: waves 0,1 -> s_sc[h][0..31] ----
        if (wv < 2) {
            f32x4 sacc = {0.f, 0.f, 0.f, 0.f};
            #pragma unroll
            for (int ks = 0; ks < 768; ks += 32) {
                bf16x8 aq = *(const bf16x8*)&qtS[fr][ks + fko];
                bf16x8 bt = *(const bf16x8*)&TF[wv * 16 + fr][ks + fko];
                sacc = __builtin_amdgcn_mfma_f32_16x16x32_bf16(aq, bt, sacc, 0, 0, 0);
            }
            if (lane < 32) {
                const int hbase = (lane >> 4) * 4;
                #pragma unroll
                for (int r = 0; r < 4; ++r)
                    s_sc[hbase + r][wv * 16 + (lane & 15)] = sacc[r];
            }
        }
        __syncthreads();   // scores ready
        // ---- online softmax ----
        {
            const int mask = att[b * 128 + s * 32 + tl];
            float sv = mask ? s_sc[h_own][tl] : -INFINITY;
            float mx = sv;
            mx = fmaxf(mx, __shfl_xor(mx, 16));
            mx = fmaxf(mx, __shfl_xor(mx, 8));
            mx = fmaxf(mx, __shfl_xor(mx, 4));
            mx = fmaxf(mx, __shfl_xor(mx, 2));
            mx = fmaxf(mx, __shfl_xor(mx, 1));
            float mnew = fmaxf(mrun, mx);
            float p = mask ? __expf(sv - mnew) : 0.f;
            float f = (mnew == -INFINITY) ? 1.f : __expf(mrun - mnew);
            float psum = p;
            psum += __shfl_xor(psum, 16);
            psum += __shfl_xor(psum, 8);
            psum += __shfl_xor(psum, 4);
            psum += __shfl_xor(psum, 2);
            psum += __shfl_xor(psum, 1);
            srun = srun * f + psum;
            mrun = mnew;
            ps[h_own][tl] = p;
            const float f0 = __shfl(f, 0);
            const float f1 = __shfl(f, 32);
            #pragma unroll
            for (int k = 0; k < 3; ++k)
                #pragma unroll
                for (int e = 0; e < 4; ++e) {
                    acc[0][k][e] *= f0;
                    acc[1][k][e] *= f1;
                }
        }
        // ---- PV (same-wave ps, no barrier) ----
        {
            #pragma unroll 8
            for (int t = 0; t < 32; ++t) {
                const float p0 = ps[h0][t];
                const float p1 = ps[h0 + 1][t];
                #pragma unroll
                for (int k = 0; k < 3; ++k) {
                    ushort4 u = *(const ushort4*)&TF[t][4 * lane + 256 * k];
                    float x0 = bf2f(u.x), x1 = bf2f(u.y), x2 = bf2f(u.z), x3 = bf2f(u.w);
                    acc[0][k][0] += p0 * x0; acc[0][k][1] += p0 * x1;
                    acc[0][k][2] += p0 * x2; acc[0][k][3] += p0 * x3;
                    acc[1][k][0] += p1 * x0; acc[1][k][1] += p1 * x1;
                    acc[1][k][2] += p1 * x2; acc[1][k][3] += p1 * x3;
                }
            }
        }
    }

    // ---- normalize + write bf16 ----
    const float sum0 = __shfl(srun, 0);
    const float sum1 = __shfl(srun, 32);
    const float i0 = 1.f / sum0, i1 = 1.f / sum1;
    #pragma unroll
    for (int k = 0; k < 3; ++k) {
        ushort4 o0, o1;
        o0.x = f2bf(acc[0][k][0] * i0); o0.y = f2bf(acc[0][k][1] * i0);
        o0.z = f2bf(acc[0][k][2] * i0); o0.w = f2bf(acc[0][k][3] * i0);
        o1.x = f2bf(acc[1][k][0] * i1); o1.y = f2bf(acc[1][k][1] * i1);
        o1.z = f2bf(acc[1][k][2] * i1); o1.w = f2bf(acc[1][k][3] * i1);
        *(ushort4*)&ctxtf[(size_t)b * 6144 + (size_t)h0 * 768 + 4 * lane + 256 * k] = o0;
        *(ushort4*)&ctxtf[(size_t)b * 6144 + (size_t)(h0 + 1) * 768 + 4 * lane + 256 * k] = o1;
    }
}

// ======================================================================
// launch
// ======================================================================
extern "C" void kernel_launch(void* const* d_in, const int* in_sizes, int n_in,
                              void* d_out, int out_size, void* d_ws, size_t ws_size,
                              hipStream_t stream)
{
    const float* x    = (const float*)d_in[0];
    const float* zc   = (const float*)d_in[1];
    const float* tf   = (const float*)d_in[2];
    const int*   att  = (const int*)d_in[3];
    const float* Wg   = (const float*)d_in[4];
    const float* bg   = (const float*)d_in[5];
    const float* Wb   = (const float*)d_in[6];
    const float* bb   = (const float*)d_in[7];
    const float* Wl   = (const float*)d_in[8];
    const float* bl   = (const float*)d_in[9];
    const float* ln1g = (const float*)d_in[10];
    const float* ln1b = (const float*)d_in[11];
    const float* Wq   = (const float*)d_in[12];
    const float* bq   = (const float*)d_in[13];
    const float* Wk   = (const float*)d_in[14];
    // d_in[15] = bk: softmax-shift-invariant, cancels exactly.
    const float* Wv   = (const float*)d_in[16];
    const float* bv   = (const float*)d_in[17];
    const float* Wo   = (const float*)d_in[18];
    const float* bo   = (const float*)d_in[19];
    const float* ln2g = (const float*)d_in[20];
    const float* ln2b = (const float*)d_in[21];

    float* ws = (float*)d_ws;
    const size_t M1 = 1u << 20;
    float* H1  = ws;              // [B,F] f32
    float* GB  = ws + 1 * M1;     // [B,2048] f32 gamma|beta
    float* AO  = ws + 3 * M1;     // [B,F] f32
    float* bgb = ws + 4 * M1;     // [2048] f32 bg|bb

    ushort* u = (ushort*)(ws + 5 * M1);
    ushort* WlB  = u;                       // 1M
    ushort* WqB  = u + 1 * M1;              // 1M
    ushort* WoB  = u + 2 * M1;              // 1M
    ushort* WvB  = u + 3 * M1;              // 768K
    ushort* WgbB = u + 3 * M1 + 786432;     // 512K [Wg|Wb][2048,256]
    ushort* WkT  = u + 3 * M1 + 1310720;    // 768K [8][768][128]
    ushort* xB   = u + 5 * M1;              // 1M
    ushort* zB   = u + 6 * M1;              // 256K
    ushort* OUTB = u + 6 * M1 + 262144;     // 1M  bf16 modulated output
    ushort* Q    = u + 7 * M1 + 262144;     // 1M  bf16
    ushort* QT   = u + 8 * M1 + 262144;     // 6M  bf16 [B,8,768]
    ushort* CTXB = u + 14 * M1 + 262144;    // 6M  bf16 [B,8,768]
    ushort* CTX  = u + 20 * M1 + 262144;    // 1M  bf16 [B,F]

    dim3 blk(256);

    // ---- prep (2 dispatches) ----
    cvt_all<<<dim3(5632), blk, 0, stream>>>(Wl, Wq, Wo, Wv, Wg, Wb, x, zc, bg, bb,
                                            WlB, WqB, WoB, WvB, WgbB, xB, zB, bgb);
    transpose_wk<<<dim3(24, 4, 8), blk, 0, stream>>>(Wk, WkT);

    // ---- h1 = x @ Wl^T + bl  (f32 out) ----
    gemm_bb<0><<<dim3(16, 16, 1), blk, 0, stream>>>(xB, 1024, 0, WlB, 1024, 0,
        (void*)H1, 1024, 0, bl, 0, 1.f, 1024);
    // ---- [gamma|beta] = z @ [Wg|Wb]^T + [bg|bb]  (f32 out) ----
    gemm_bb<0><<<dim3(32, 16, 1), blk, 0, stream>>>(zB, 256, 0, WgbB, 256, 0,
        (void*)GB, 2048, 0, bgb, 0, 1.f, 256);
    // ---- outb = LN(h1)*(1+gamma)+beta  (bf16) ----
    rowops1<<<dim3(1024), blk, 0, stream>>>(H1, GB, ln1g, ln1b, OUTB);
    // ---- q = outb @ Wq^T + bq  (bf16 out) ----
    gemm_bb<1><<<dim3(16, 16, 1), blk, 0, stream>>>(OUTB, 1024, 0, WqB, 1024, 0,
        (void*)Q, 1024, 0, bq, 0, 1.f, 1024);
    // ---- qt[b,h,:] = (1/sqrt(128)) * q[b,h,:] @ Wk_h  (bf16 out) ----
    gemm_bb<1><<<dim3(12, 16, 8), blk, 0, stream>>>(Q, 1024, 128, WkT, 128, 98304,
        (void*)QT, 6144, 768, nullptr, 0, 0.08838834764831845f, 128);
    // ---- fused single-pass attention (bf16 out) ----
    attn_fused<<<dim3(1024), blk, 0, stream>>>(tf, QT, att, CTXB);
    // ---- ctx = ctxtf @ Wv_h^T + bv  (bf16 out) ----
    gemm_bb<1><<<dim3(2, 16, 8), blk, 0, stream>>>(CTXB, 6144, 768, WvB, 768, 98304,
        (void*)CTX, 1024, 128, bv, 128, 1.f, 768);
    // ---- attn_out = ctx @ Wo^T + bo  (f32 out) ----
    gemm_bb<0><<<dim3(16, 16, 1), blk, 0, stream>>>(CTX, 1024, 0, WoB, 1024, 0,
        (void*)AO, 1024, 0, bo, 0, 1.f, 1024);
    // ---- final = gelu(outb + LN(attn_out)) ----
    rowops2<<<dim3(1024), blk, 0, stream>>>(OUTB, AO, ln2g, ln2b, (float*)d_out);
}